// Round 1
// baseline (189.121 us; speedup 1.0000x reference)
//
#include <hip/hip_runtime.h>
#include <hip/hip_bf16.h>

// PositionEncoding: out[b,o,n,k] = W2 @ relu(W1 @ (coords[b,:,n] - coords[b,:,idx[b,n,k]]) + b1) + b2
// B=4, C=3, N=32768, K=16, OUT=64.
// Structure: 1 wave per point n (16 neighbors = 16 MFMA columns).
// Layer 1 (3->64) on VALU f32 per lane (W1/b1 register-resident),
// layer 2 (64->64) on bf16 MFMA (4 m-tiles x 2 K-steps of 16x16x32).
// No LDS, no barriers. HBM-write-bound by the 512 MiB f32 output.

typedef __attribute__((ext_vector_type(8))) short bf16x8;   // 8 bf16 in 4 VGPRs
typedef __attribute__((ext_vector_type(4))) float f32x4;

#define N_PTS 32768
#define K_NB  16
#define C_OUT 64
#define NPW   8     // points per wave

__device__ __forceinline__ short f2b(float x) {
    __hip_bfloat16 h = __float2bfloat16(x);   // RNE
    return reinterpret_cast<short&>(h);
}

__global__ __launch_bounds__(256) void pe_kernel(
    const float* __restrict__ coords,   // (B, 3, N)
    const int*   __restrict__ knn,      // (B, N, K) int32
    const float* __restrict__ W1,       // (64, 3)
    const float* __restrict__ b1,       // (64,)
    const float* __restrict__ W2,       // (64, 64)
    const float* __restrict__ b2,       // (64,)
    float*       __restrict__ out)      // (B, 64, N, K)
{
    const int lane = (int)(threadIdx.x & 63);
    const int wid  = (int)(threadIdx.x >> 6);
    const int g    = lane >> 4;     // k-group 0..3 (K-dim sub-slot)
    const int q    = lane & 15;     // MFMA row/col index within tile

    // ---- per-lane weights, loaded once ----
    // Lane's 16 hidden-j's (per assumed k-mapping j = 32*s + 8*g + i).
    float w1r[2][8][3], b1r[2][8];
#pragma unroll
    for (int s = 0; s < 2; ++s)
#pragma unroll
        for (int i = 0; i < 8; ++i) {
            int j = 32 * s + 8 * g + i;
            w1r[s][i][0] = W1[j * 3 + 0];
            w1r[s][i][1] = W1[j * 3 + 1];
            w1r[s][i][2] = W1[j * 3 + 2];
            b1r[s][i]    = b1[j];
        }

    // A-fragments: W2[o][j], o-row = q, j = 32*s + 8*g + i (same k-mapping as B).
    bf16x8 afrag[4][2];
#pragma unroll
    for (int mt = 0; mt < 4; ++mt)
#pragma unroll
        for (int s = 0; s < 2; ++s)
#pragma unroll
            for (int i = 0; i < 8; ++i)
                afrag[mt][s][i] = f2b(W2[(16 * mt + q) * 64 + 32 * s + 8 * g + i]);

    // b2 per lane for acc init: D row = (lane>>4)*4 + r  ->  o = 16*mt + 4*g + r.
    float b2r[4][4];
#pragma unroll
    for (int mt = 0; mt < 4; ++mt)
#pragma unroll
        for (int r = 0; r < 4; ++r)
            b2r[mt][r] = b2[16 * mt + 4 * g + r];

    int col0 = ((int)blockIdx.x * 4 + wid) * NPW;

    for (int t = 0; t < NPW; ++t) {
        int col = __builtin_amdgcn_readfirstlane(col0 + t);  // wave-uniform column
        int b = col >> 15;            // col / N
        int n = col & (N_PTS - 1);    // col % N

        // neighbor index for this lane's column k=q (4-way redundant across g)
        int idx = knn[((b << 15) + n) * K_NB + q];

        const float* cb = coords + (size_t)b * (3 * N_PTS);
        float d0 = cb[n]             - cb[idx];
        float d1 = cb[N_PTS + n]     - cb[N_PTS + idx];
        float d2 = cb[2 * N_PTS + n] - cb[2 * N_PTS + idx];

        // layer 1 + relu + cvt -> B-fragments H[j][k=q]
        bf16x8 bfrag[2];
#pragma unroll
        for (int s = 0; s < 2; ++s)
#pragma unroll
            for (int i = 0; i < 8; ++i) {
                float h = fmaf(w1r[s][i][0], d0,
                          fmaf(w1r[s][i][1], d1,
                          fmaf(w1r[s][i][2], d2, b1r[s][i])));
                h = fmaxf(h, 0.0f);
                bfrag[s][i] = f2b(h);
            }

        // layer 2 on MFMA: D(64x16) = W2(64x64) @ H(64x16), acc init = b2
        f32x4 acc[4];
#pragma unroll
        for (int mt = 0; mt < 4; ++mt) {
            acc[mt][0] = b2r[mt][0];
            acc[mt][1] = b2r[mt][1];
            acc[mt][2] = b2r[mt][2];
            acc[mt][3] = b2r[mt][3];
        }
#pragma unroll
        for (int mt = 0; mt < 4; ++mt)
#pragma unroll
            for (int s = 0; s < 2; ++s)
                acc[mt] = __builtin_amdgcn_mfma_f32_16x16x32_bf16(
                              afrag[mt][s], bfrag[s], acc[mt], 0, 0, 0);

        // store: out[((b*64 + o)*N + n)*16 + k], o = 16*mt + 4*g + r, k = q
        float* outp = out + (size_t)b * (C_OUT * (size_t)N_PTS * K_NB)
                          + (size_t)n * K_NB + q;
        const size_t ostride = (size_t)N_PTS * K_NB;
#pragma unroll
        for (int mt = 0; mt < 4; ++mt)
#pragma unroll
            for (int r = 0; r < 4; ++r)
                outp[(size_t)(16 * mt + 4 * g + r) * ostride] = acc[mt][r];
    }
}

extern "C" void kernel_launch(void* const* d_in, const int* in_sizes, int n_in,
                              void* d_out, int out_size, void* d_ws, size_t ws_size,
                              hipStream_t stream) {
    const float* coords = (const float*)d_in[0];
    const int*   knn    = (const int*)d_in[1];
    const float* W1     = (const float*)d_in[2];
    const float* b1     = (const float*)d_in[3];
    const float* W2     = (const float*)d_in[4];
    const float* b2     = (const float*)d_in[5];
    float* out = (float*)d_out;

    // columns = B*N = 131072; 4 waves/block, 8 points/wave -> 4096 blocks
    dim3 grid(4096), block(256);
    hipLaunchKernelGGL(pe_kernel, grid, block, 0, stream,
                       coords, knn, W1, b1, W2, b2, out);
}

// Round 2
// 169.181 us; speedup vs baseline: 1.1179x; 1.1179x over previous
//
#include <hip/hip_runtime.h>
#include <hip/hip_bf16.h>

// PositionEncoding: out[b,o,n,k] = W2 @ relu(W1 @ (coords[b,:,n] - coords[b,:,idx[b,n,k]]) + b1) + b2
// B=4, C=3, N=32768, K=16, OUT=64.
// One wave per point n; layer 1 (3->64) on f32 VALU, layer 2 (64->64) on bf16 MFMA.
// Round 1 change: swapped MFMA operands -> D[k][o] tile, so each lane holds 4
// consecutive k values => float4 nontemporal stores (4 dwordx4/pt vs 16 dword/pt).

typedef __attribute__((ext_vector_type(8))) short bf16x8;   // 8 bf16 in 4 VGPRs
typedef __attribute__((ext_vector_type(4))) float f32x4;

#define N_PTS 32768
#define K_NB  16
#define C_OUT 64
#define NPW   8     // points per wave

__device__ __forceinline__ short f2b(float x) {
    __hip_bfloat16 h = __float2bfloat16(x);   // RNE
    return reinterpret_cast<short&>(h);
}

__global__ __launch_bounds__(256) void pe_kernel(
    const float* __restrict__ coords,   // (B, 3, N)
    const int*   __restrict__ knn,      // (B, N, K) int32
    const float* __restrict__ W1,       // (64, 3)
    const float* __restrict__ b1,       // (64,)
    const float* __restrict__ W2,       // (64, 64)
    const float* __restrict__ b2,       // (64,)
    float*       __restrict__ out)      // (B, 64, N, K)
{
    const int lane = (int)(threadIdx.x & 63);
    const int wid  = (int)(threadIdx.x >> 6);
    const int g    = lane >> 4;     // hi 2 bits: k-dim sub-slot
    const int q    = lane & 15;     // MFMA row/col index within tile

    // ---- per-lane weights, loaded once ----
    // Lane's 16 hidden-j's (assumed k-mapping j = 32*s + 8*g + i, consistent
    // across A and B so any HW k-permutation cancels).
    float w1r[2][8][3], b1r[2][8];
#pragma unroll
    for (int s = 0; s < 2; ++s)
#pragma unroll
        for (int i = 0; i < 8; ++i) {
            int j = 32 * s + 8 * g + i;
            w1r[s][i][0] = W1[j * 3 + 0];
            w1r[s][i][1] = W1[j * 3 + 1];
            w1r[s][i][2] = W1[j * 3 + 2];
            b1r[s][i]    = b1[j];
        }

    // W2 fragments (used as the B operand): element = W2[16*mt+q][32*s+8*g+i].
    bf16x8 wfrag[4][2];
#pragma unroll
    for (int mt = 0; mt < 4; ++mt)
#pragma unroll
        for (int s = 0; s < 2; ++s)
#pragma unroll
            for (int i = 0; i < 8; ++i)
                wfrag[mt][s][i] = f2b(W2[(16 * mt + q) * 64 + 32 * s + 8 * g + i]);

    // D[k][o]: lane (g,q) holds o = 16*mt + q (all 4 regs), k = 4*g + r.
    float b2r[4];
#pragma unroll
    for (int mt = 0; mt < 4; ++mt)
        b2r[mt] = b2[16 * mt + q];

    int col0 = ((int)blockIdx.x * 4 + wid) * NPW;

#pragma unroll 2
    for (int t = 0; t < NPW; ++t) {
        int col = __builtin_amdgcn_readfirstlane(col0 + t);  // wave-uniform point
        int b = col >> 15;            // col / N
        int n = col & (N_PTS - 1);    // col % N

        // neighbor index for this lane's k = q (4-way redundant across g)
        int idx = knn[((b << 15) + n) * K_NB + q];

        const float* cb = coords + (size_t)b * (3 * N_PTS);
        float d0 = cb[n]             - cb[idx];
        float d1 = cb[N_PTS + n]     - cb[N_PTS + idx];
        float d2 = cb[2 * N_PTS + n] - cb[2 * N_PTS + idx];

        // layer 1 + relu + cvt: H[j = 32s+8g+i][k = q]  (A operand)
        bf16x8 hfrag[2];
#pragma unroll
        for (int s = 0; s < 2; ++s)
#pragma unroll
            for (int i = 0; i < 8; ++i) {
                float h = fmaf(w1r[s][i][0], d0,
                          fmaf(w1r[s][i][1], d1,
                          fmaf(w1r[s][i][2], d2, b1r[s][i])));
                h = fmaxf(h, 0.0f);
                hfrag[s][i] = f2b(h);
            }

        // layer 2: D[k][o] = H^T(16x64) @ W2^T(64x16-per-tile), acc init = b2[o]
        f32x4 acc[4];
#pragma unroll
        for (int mt = 0; mt < 4; ++mt) {
            acc[mt][0] = b2r[mt];
            acc[mt][1] = b2r[mt];
            acc[mt][2] = b2r[mt];
            acc[mt][3] = b2r[mt];
        }
#pragma unroll
        for (int mt = 0; mt < 4; ++mt)
#pragma unroll
            for (int s = 0; s < 2; ++s)
                acc[mt] = __builtin_amdgcn_mfma_f32_16x16x32_bf16(
                              hfrag[s], wfrag[mt][s], acc[mt], 0, 0, 0);

        // store: out[((b*64 + 16*mt + q)*N + n)*16 + 4*g .. +3]  (float4, NT)
        const size_t base = ((size_t)(b * C_OUT + q) * N_PTS + n) * K_NB + 4 * g;
        const size_t mtstride = (size_t)16 * N_PTS * K_NB;
#pragma unroll
        for (int mt = 0; mt < 4; ++mt)
            __builtin_nontemporal_store(acc[mt],
                (f32x4*)(out + base + (size_t)mt * mtstride));
    }
}

extern "C" void kernel_launch(void* const* d_in, const int* in_sizes, int n_in,
                              void* d_out, int out_size, void* d_ws, size_t ws_size,
                              hipStream_t stream) {
    const float* coords = (const float*)d_in[0];
    const int*   knn    = (const int*)d_in[1];
    const float* W1     = (const float*)d_in[2];
    const float* b1     = (const float*)d_in[3];
    const float* W2     = (const float*)d_in[4];
    const float* b2     = (const float*)d_in[5];
    float* out = (float*)d_out;

    // columns = B*N = 131072; 4 waves/block, 8 points/wave -> 4096 blocks
    dim3 grid(4096), block(256);
    hipLaunchKernelGGL(pe_kernel, grid, block, 0, stream,
                       coords, knn, W1, b1, W2, b2, out);
}

// Round 3
// 102.911 us; speedup vs baseline: 1.8377x; 1.6440x over previous
//
#include <hip/hip_runtime.h>
#include <hip/hip_bf16.h>

// PositionEncoding: out[b,o,n,k] = W2 @ relu(W1 @ (coords[b,:,n] - coords[b,:,idx[b,n,k]]) + b1) + b2
// B=4, C=3, N=32768, K=16, OUT=64.
// One wave per pair of consecutive points; layer 1 (3->64) f32 VALU, layer 2
// (64->64) bf16 MFMA (swapped operands -> D[k][o] tile).
// Round 2 change: epilogue repack through per-wave LDS so every global store
// writes FULL 128B lines (a 128B line = 2 consecutive points' 64B k-rows).
// Previous rounds wrote 64B halves scattered 2MiB apart -> ~2x HBM write traffic.

typedef __attribute__((ext_vector_type(8))) short bf16x8;   // 8 bf16 in 4 VGPRs
typedef __attribute__((ext_vector_type(4))) float f32x4;

#define N_PTS 32768
#define K_NB  16
#define C_OUT 64
#define NPW   8     // points per wave (4 pairs)

__device__ __forceinline__ short f2b(float x) {
    __hip_bfloat16 h = __float2bfloat16(x);   // RNE
    return reinterpret_cast<short&>(h);
}

__global__ __launch_bounds__(256) void pe_kernel(
    const float* __restrict__ coords,   // (B, 3, N)
    const int*   __restrict__ knn,      // (B, N, K) int32
    const float* __restrict__ W1,       // (64, 3)
    const float* __restrict__ b1,       // (64,)
    const float* __restrict__ W2,       // (64, 64)
    const float* __restrict__ b2,       // (64,)
    float*       __restrict__ out)      // (B, 64, N, K)
{
    const int lane = (int)(threadIdx.x & 63);
    const int wid  = (int)(threadIdx.x >> 6);
    const int g    = lane >> 4;     // hi 2 bits of lane
    const int q    = lane & 15;     // MFMA row/col index within tile

    // per-wave-private repack buffer: 64 o-rows x 128B ([pt0 k0..15][pt1 k0..15])
    // chunk swizzle: 16B-chunk c stored at c ^ (o&7)
    __shared__ float lds[4][C_OUT * 32];
    float* myl = lds[wid];

    // ---- per-lane weights, loaded once ----
    // Lane's 16 hidden-j's (k-mapping j = 32*s + 8*g + i, consistent across
    // A and B fragments so any HW k-permutation cancels).
    float w1r[2][8][3], b1r[2][8];
#pragma unroll
    for (int s = 0; s < 2; ++s)
#pragma unroll
        for (int i = 0; i < 8; ++i) {
            int j = 32 * s + 8 * g + i;
            w1r[s][i][0] = W1[j * 3 + 0];
            w1r[s][i][1] = W1[j * 3 + 1];
            w1r[s][i][2] = W1[j * 3 + 2];
            b1r[s][i]    = b1[j];
        }

    // W2 fragments (B operand): element = W2[16*mt+q][32*s+8*g+i].
    bf16x8 wfrag[4][2];
#pragma unroll
    for (int mt = 0; mt < 4; ++mt)
#pragma unroll
        for (int s = 0; s < 2; ++s)
#pragma unroll
            for (int i = 0; i < 8; ++i)
                wfrag[mt][s][i] = f2b(W2[(16 * mt + q) * 64 + 32 * s + 8 * g + i]);

    // D[k][o]: lane (g,q) holds o = 16*mt + q (all 4 regs), k = 4*g + r.
    float b2r[4];
#pragma unroll
    for (int mt = 0; mt < 4; ++mt)
        b2r[mt] = b2[16 * mt + q];

    const int col0 = ((int)blockIdx.x * 4 + wid) * NPW;

    for (int tp = 0; tp < NPW / 2; ++tp) {
        const int col = __builtin_amdgcn_readfirstlane(col0 + 2 * tp);
        const int b  = col >> 15;           // col / N
        const int n0 = col & (N_PTS - 1);   // even point; pair = {n0, n0+1}

        const int*   kb = knn + ((size_t)(b << 15) + n0) * K_NB;
        const float* cb = coords + (size_t)b * (3 * N_PTS);

        // neighbor indices for this lane's k = q, both points
        int i0 = kb[q];
        int i1 = kb[K_NB + q];

        float e0 = cb[n0];            // wave-uniform (scalar loads)
        float e1 = cb[N_PTS + n0];
        float e2 = cb[2 * N_PTS + n0];
        float f0 = cb[n0 + 1];
        float f1 = cb[N_PTS + n0 + 1];
        float f2 = cb[2 * N_PTS + n0 + 1];

        float a0 = e0 - cb[i0];
        float a1 = e1 - cb[N_PTS + i0];
        float a2 = e2 - cb[2 * N_PTS + i0];
        float c0 = f0 - cb[i1];
        float c1 = f1 - cb[N_PTS + i1];
        float c2 = f2 - cb[2 * N_PTS + i1];

        // layer 1 + relu + cvt for both points: H[j][k=q] (A operand)
        bf16x8 h0[2], h1[2];
#pragma unroll
        for (int s = 0; s < 2; ++s)
#pragma unroll
            for (int i = 0; i < 8; ++i) {
                float u = fmaf(w1r[s][i][0], a0,
                          fmaf(w1r[s][i][1], a1,
                          fmaf(w1r[s][i][2], a2, b1r[s][i])));
                h0[s][i] = f2b(fmaxf(u, 0.0f));
                float v = fmaf(w1r[s][i][0], c0,
                          fmaf(w1r[s][i][1], c1,
                          fmaf(w1r[s][i][2], c2, b1r[s][i])));
                h1[s][i] = f2b(fmaxf(v, 0.0f));
            }

        // layer 2 on MFMA + stash into LDS (chunk = 4*p + g, swizzled by o&7=q&7)
#pragma unroll
        for (int p = 0; p < 2; ++p) {
#pragma unroll
            for (int mt = 0; mt < 4; ++mt) {
                f32x4 acc = { b2r[mt], b2r[mt], b2r[mt], b2r[mt] };
#pragma unroll
                for (int s = 0; s < 2; ++s)
                    acc = __builtin_amdgcn_mfma_f32_16x16x32_bf16(
                              (p == 0 ? h0[s] : h1[s]), wfrag[mt][s], acc, 0, 0, 0);
                const int o = 16 * mt + q;
                const int chunk = (4 * p + g) ^ (q & 7);
                *(f32x4*)(myl + o * 32 + chunk * 4) = acc;
            }
        }

        // cooperative store: 8 instrs, each = 8 full 128B lines (8 lanes x 16B)
        const int r = lane >> 3;      // row within 8-row group
        const int c = lane & 7;       // 16B chunk within 128B line
        const int cs = c ^ r;         // swizzled LDS chunk (o&7 == r)
        const size_t nbase = ((size_t)(b * C_OUT) * N_PTS + n0) * K_NB + c * 4;
        const size_t ostride = (size_t)N_PTS * K_NB;
#pragma unroll
        for (int i = 0; i < 8; ++i) {
            const int o = 8 * i + r;
            f32x4 vdat = *(const f32x4*)(myl + o * 32 + cs * 4);
            __builtin_nontemporal_store(vdat,
                (f32x4*)(out + nbase + (size_t)o * ostride));
        }
    }
}

extern "C" void kernel_launch(void* const* d_in, const int* in_sizes, int n_in,
                              void* d_out, int out_size, void* d_ws, size_t ws_size,
                              hipStream_t stream) {
    const float* coords = (const float*)d_in[0];
    const int*   knn    = (const int*)d_in[1];
    const float* W1     = (const float*)d_in[2];
    const float* b1     = (const float*)d_in[3];
    const float* W2     = (const float*)d_in[4];
    const float* b2     = (const float*)d_in[5];
    float* out = (float*)d_out;

    // 131072 points / 8 per wave / 4 waves per block -> 4096 blocks
    dim3 grid(4096), block(256);
    hipLaunchKernelGGL(pe_kernel, grid, block, 0, stream,
                       coords, knn, W1, b1, W2, b2, out);
}

// Round 4
// 102.808 us; speedup vs baseline: 1.8396x; 1.0010x over previous
//
#include <hip/hip_runtime.h>
#include <hip/hip_bf16.h>

// PositionEncoding: out[b,o,n,k] = W2 @ relu(W1 @ (coords[b,:,n] - coords[b,:,idx[b,n,k]]) + b1) + b2
// B=4, C=3, N=32768, K=16, OUT=64.
// One wave per group of 4 consecutive points; layer 1 (3->64) f32 VALU,
// layer 2 (64->64) bf16 MFMA (swapped operands -> D[k][o] tile).
// Round 3 change: batch 4 points per LDS repack tile, split o-range in half
// (o 0..31 then 32..63) so LDS stays 8KiB/wave. Each global store instruction
// now writes 4 o-rows x 256B CONTIGUOUS (vs 8 rows x 128B) -> fewer, fatter
// 2MiB-strided DRAM streams per instruction.

typedef __attribute__((ext_vector_type(8))) short bf16x8;   // 8 bf16 in 4 VGPRs
typedef __attribute__((ext_vector_type(4))) float f32x4;

#define N_PTS 32768
#define K_NB  16
#define C_OUT 64
#define NPW   8     // points per wave (2 quads)

__device__ __forceinline__ short f2b(float x) {
    __hip_bfloat16 h = __float2bfloat16(x);   // RNE
    return reinterpret_cast<short&>(h);
}

__global__ __launch_bounds__(256) void pe_kernel(
    const float* __restrict__ coords,   // (B, 3, N)
    const int*   __restrict__ knn,      // (B, N, K) int32
    const float* __restrict__ W1,       // (64, 3)
    const float* __restrict__ b1,       // (64,)
    const float* __restrict__ W2,       // (64, 64)
    const float* __restrict__ b2,       // (64,)
    float*       __restrict__ out)      // (B, 64, N, K)
{
    const int lane = (int)(threadIdx.x & 63);
    const int wid  = (int)(threadIdx.x >> 6);
    const int g    = lane >> 4;     // hi 2 bits of lane
    const int q    = lane & 15;     // MFMA row/col index within tile

    // per-wave repack buffer: 32 o-rows x 256B (4 pts x 16 k x 4B per row)
    // 16B-chunk ch (memory order 4*p+g) stored at ch ^ (row&15)
    __shared__ float lds[4][32 * 64];
    float* myl = lds[wid];

    // ---- per-lane weights, loaded once ----
    // Lane's 16 hidden-j's (k-mapping j = 32*s + 8*g + i, consistent across
    // A and B fragments so any HW k-permutation cancels).
    float w1r[2][8][3], b1r[2][8];
#pragma unroll
    for (int s = 0; s < 2; ++s)
#pragma unroll
        for (int i = 0; i < 8; ++i) {
            int j = 32 * s + 8 * g + i;
            w1r[s][i][0] = W1[j * 3 + 0];
            w1r[s][i][1] = W1[j * 3 + 1];
            w1r[s][i][2] = W1[j * 3 + 2];
            b1r[s][i]    = b1[j];
        }

    // W2 fragments (B operand): element = W2[16*mt+q][32*s+8*g+i].
    bf16x8 wfrag[4][2];
#pragma unroll
    for (int mt = 0; mt < 4; ++mt)
#pragma unroll
        for (int s = 0; s < 2; ++s)
#pragma unroll
            for (int i = 0; i < 8; ++i)
                wfrag[mt][s][i] = f2b(W2[(16 * mt + q) * 64 + 32 * s + 8 * g + i]);

    // D[k][o]: lane (g,q) holds o = 16*mt + q (all 4 regs), k = 4*g + r.
    float b2r[4];
#pragma unroll
    for (int mt = 0; mt < 4; ++mt)
        b2r[mt] = b2[16 * mt + q];

    const int col0 = ((int)blockIdx.x * 4 + wid) * NPW;

#pragma unroll 1
    for (int tq = 0; tq < NPW / 4; ++tq) {
        const int col = __builtin_amdgcn_readfirstlane(col0 + 4 * tq);
        const int b  = col >> 15;           // col / N
        const int n0 = col & (N_PTS - 1);   // quad-aligned; points n0..n0+3

        const int*   kb = knn + ((size_t)(b << 15) + n0) * K_NB;
        const float* cb = coords + (size_t)b * (3 * N_PTS);

        // neighbor indices for this lane's k = q, all 4 points
        int idxp[4];
#pragma unroll
        for (int p = 0; p < 4; ++p)
            idxp[p] = kb[K_NB * p + q];

        // relative coords for 4 points (centers are wave-uniform scalar loads)
        float d[4][3];
#pragma unroll
        for (int p = 0; p < 4; ++p) {
            d[p][0] = cb[n0 + p]             - cb[idxp[p]];
            d[p][1] = cb[N_PTS + n0 + p]     - cb[N_PTS + idxp[p]];
            d[p][2] = cb[2 * N_PTS + n0 + p] - cb[2 * N_PTS + idxp[p]];
        }

        // layer 1 + relu + cvt: H[j][k=q] per point (A operand)
        bf16x8 hfrag[4][2];
#pragma unroll
        for (int p = 0; p < 4; ++p)
#pragma unroll
            for (int s = 0; s < 2; ++s)
#pragma unroll
                for (int i = 0; i < 8; ++i) {
                    float u = fmaf(w1r[s][i][0], d[p][0],
                              fmaf(w1r[s][i][1], d[p][1],
                              fmaf(w1r[s][i][2], d[p][2], b1r[s][i])));
                    hfrag[p][s][i] = f2b(fmaxf(u, 0.0f));
                }

        const size_t ostride = (size_t)N_PTS * K_NB;
        const size_t nbase = ((size_t)(b * C_OUT) * N_PTS + n0) * K_NB;

#pragma unroll
        for (int half = 0; half < 2; ++half) {
            // MFMA for o in [32*half, 32*half+32), all 4 points -> LDS
#pragma unroll
            for (int p = 0; p < 4; ++p)
#pragma unroll
                for (int mtl = 0; mtl < 2; ++mtl) {
                    const int mt = 2 * half + mtl;
                    f32x4 acc = { b2r[mt], b2r[mt], b2r[mt], b2r[mt] };
#pragma unroll
                    for (int s = 0; s < 2; ++s)
                        acc = __builtin_amdgcn_mfma_f32_16x16x32_bf16(
                                  hfrag[p][s], wfrag[mt][s], acc, 0, 0, 0);
                    const int row = 16 * mtl + q;          // o - 32*half
                    const int ch  = (4 * p + g) ^ (row & 15);
                    *(f32x4*)(myl + row * 64 + ch * 4) = acc;
                }

            // cooperative store: 8 instrs, each 4 o-rows x 256B contiguous
            const int rin  = lane >> 4;     // row-in-4 group
            const int chm  = lane & 15;     // memory 16B-chunk within 256B row
#pragma unroll
            for (int i = 0; i < 8; ++i) {
                const int row = 4 * i + rin;              // o - 32*half
                const int chl = chm ^ (row & 15);         // swizzled LDS chunk
                f32x4 vdat = *(const f32x4*)(myl + row * 64 + chl * 4);
                const int o = 32 * half + row;
                __builtin_nontemporal_store(vdat,
                    (f32x4*)(out + nbase + (size_t)o * ostride + chm * 4));
            }
        }
    }
}

extern "C" void kernel_launch(void* const* d_in, const int* in_sizes, int n_in,
                              void* d_out, int out_size, void* d_ws, size_t ws_size,
                              hipStream_t stream) {
    const float* coords = (const float*)d_in[0];
    const int*   knn    = (const int*)d_in[1];
    const float* W1     = (const float*)d_in[2];
    const float* b1     = (const float*)d_in[3];
    const float* W2     = (const float*)d_in[4];
    const float* b2     = (const float*)d_in[5];
    float* out = (float*)d_out;

    // 131072 points / 8 per wave / 4 waves per block -> 4096 blocks
    dim3 grid(4096), block(256);
    hipLaunchKernelGGL(pe_kernel, grid, block, 0, stream,
                       coords, knn, W1, b1, W2, b2, out);
}